// Round 19
// baseline (21.372 us; speedup 1.0000x reference)
//
#include <hip/hip_runtime.h>

#define TPL_SIZE 16384
#define TPL_K 16
#define TPL_ND 5
#define TPL_BLK 512
#define TPL_PTS 4                                  // points per thread
#define TPL_SPAN (TPL_BLK * TPL_PTS)               // 2048 points per block
#define TPL_BPB (TPL_SIZE / TPL_SPAN)              // 8 blocks per batch
#define TPL_NXCD 8

typedef __attribute__((ext_vector_type(2))) float f32x2;

// R19 = R18 (20.3 us) + LDS-gather pipelining: point p+1's 16 ds_read_b64
// are issued between p's accumulate and p's solve, so their ~120+cy latency
// hides under the ~400cy serial solve instead of stalling the next
// iteration's accumulate. ids for p+1 are already in the depth-2 register
// pipeline (issued at p-1), so no new global traffic -- pure reordering.
// Cost: +32 VGPR (nb_next). Spill tell = WRITE_SIZE.
// Ledger: u16 LDS table (R7), XCD remap (R8), rcp solve (R10), packed
// accumulation (R11), depth-2 edge/dist prefetch (R18), 512-thr blocks
// (512,2) -> 128-VGPR cap (R7/R16).
__global__ __launch_bounds__(TPL_BLK, 2) void tp_lds_kernel(
    const float* __restrict__ x,
    const float* __restrict__ points,
    const int*   __restrict__ edge_index,
    const float* __restrict__ dtp,
    const float* __restrict__ dist,
    const float* __restrict__ weight,
    float* __restrict__ out)
{
    extern __shared__ uint2 lds_pv[];   // [TPL_SIZE] = 128 KB

    const int tid = threadIdx.x;
    const int blk = blockIdx.x;

    // blk -> (batch, chunk): xcd = blk&7 ; 4 batches per XCD
    const int xcd   = blk & (TPL_NXCD - 1);
    const int batch = xcd * 4 + (blk >> 6);          // [0,32)
    const int chunk = (blk >> 3) & (TPL_BPB - 1);    // [0,8)

    const size_t base = (size_t)batch * TPL_SIZE + chunk * TPL_SPAN;

    // ---- depth-2 prologue: issue points 0 AND 1's streaming loads FIRST
    int4   ci2[2][4];
    float4 cw2[2][4];
    #pragma unroll
    for (int d = 0; d < 2; ++d) {
        const size_t rw = base + d * TPL_BLK + tid;
        const int4*   ei = reinterpret_cast<const int4*>(edge_index + rw * TPL_K);
        const float4* dw = reinterpret_cast<const float4*>(dist      + rw * TPL_K);
        #pragma unroll
        for (int q = 0; q < 4; ++q) { ci2[d][q] = ei[q]; cw2[d][q] = dw[q]; }
    }

    // ---- stage + quantize the whole batch table into LDS (coalesced) ----
    {
        const float4* pb4 = reinterpret_cast<const float4*>(points + (size_t)batch * TPL_SIZE * 2);
        const float2* xb2 = reinterpret_cast<const float2*>(x + (size_t)batch * TPL_SIZE);
        uint4* lds4 = reinterpret_cast<uint4*>(lds_pv);
        #pragma unroll
        for (int k = 0; k < TPL_SIZE / (2 * TPL_BLK); ++k) {   // 16 iters
            int g = k * TPL_BLK + tid;        // pair-group index
            float4 pp = pb4[g];               // points for entries 2g, 2g+1
            float2 xv = xb2[g];               // values for entries 2g, 2g+1
            unsigned ux0 = (unsigned)(pp.x * 65536.0f);
            unsigned uy0 = (unsigned)(pp.y * 65536.0f);
            unsigned ux1 = (unsigned)(pp.z * 65536.0f);
            unsigned uy1 = (unsigned)(pp.w * 65536.0f);
            if (ux0 > 65535u) ux0 = 65535u;
            if (uy0 > 65535u) uy0 = 65535u;
            if (ux1 > 65535u) ux1 = 65535u;
            if (uy1 > 65535u) uy1 = 65535u;
            uint4 wv;
            wv.x = ux0 | (uy0 << 16);
            wv.y = __float_as_uint(xv.x);
            wv.z = ux1 | (uy1 << 16);
            wv.w = __float_as_uint(xv.y);
            lds4[g] = wv;
        }
    }
    __syncthreads();

    const float wt0 = weight[0], wt1 = weight[1], wt2 = weight[2],
                wt3 = weight[3], wt4 = weight[4];
    const float dtv = dtp[0];

    // ---- prologue gather for point 0 ----
    uint2 nb_cur[TPL_K];
    #pragma unroll
    for (int q = 0; q < 4; ++q) {
        nb_cur[4*q+0] = lds_pv[ci2[0][q].x];
        nb_cur[4*q+1] = lds_pv[ci2[0][q].y];
        nb_cur[4*q+2] = lds_pv[ci2[0][q].z];
        nb_cur[4*q+3] = lds_pv[ci2[0][q].w];
    }

    #pragma unroll
    for (int p = 0; p < TPL_PTS; ++p) {
        const int    s   = chunk * TPL_SPAN + p * TPL_BLK + tid;
        const size_t row = base + p * TPL_BLK + tid;

        // weights for p (from slot p&1, compile-time after unroll)
        float wgt[TPL_K];
        #pragma unroll
        for (int q = 0; q < 4; ++q) {
            wgt[4*q+0] = cw2[p & 1][q].x;
            wgt[4*q+1] = cw2[p & 1][q].y;
            wgt[4*q+2] = cw2[p & 1][q].z;
            wgt[4*q+3] = cw2[p & 1][q].w;
        }

        // refill freed slot with point p+2's global loads (depth-2 pipeline)
        if (p + 2 < TPL_PTS) {
            const size_t rw = base + (p + 2) * TPL_BLK + tid;
            const int4*   ei = reinterpret_cast<const int4*>(edge_index + rw * TPL_K);
            const float4* dw = reinterpret_cast<const float4*>(dist      + rw * TPL_K);
            #pragma unroll
            for (int q = 0; q < 4; ++q) { ci2[p & 1][q] = ei[q]; cw2[p & 1][q] = dw[q]; }
        }

        // self point from LDS (same quantization as neighbors)
        uint2 se = lds_pv[s];
        const int sx = (int)(se.x & 0xffffu);
        const int sy = (int)(se.x >> 16);
        const float sv = __uint_as_float(se.y);

        // ---- packed accumulation over nb_cur ----
        f32x2 ata2[15], atb2[TPL_ND];
        #pragma unroll
        for (int i = 0; i < 15; ++i) ata2[i] = (f32x2)0.0f;
        #pragma unroll
        for (int i = 0; i < TPL_ND; ++i) atb2[i] = (f32x2)0.0f;

        #pragma unroll
        for (int tt = 0; tt < TPL_K / 2; ++tt) {
            const int t0 = 2 * tt, t1 = 2 * tt + 1;
            int dxi0 = (int)(nb_cur[t0].x & 0xffffu) - sx;
            int dyi0 = (int)(nb_cur[t0].x >> 16)     - sy;
            int dxi1 = (int)(nb_cur[t1].x & 0xffffu) - sx;
            int dyi1 = (int)(nb_cur[t1].x >> 16)     - sy;
            f32x2 dx = (f32x2){(float)dxi0, (float)dxi1} * 0x1p-16f;
            f32x2 dy = (f32x2){(float)dyi0, (float)dyi1} * 0x1p-16f;
            f32x2 w  = {wgt[t0], wgt[t1]};
            f32x2 nv = {__uint_as_float(nb_cur[t0].y), __uint_as_float(nb_cur[t1].y)};
            f32x2 hw = w * 0.5f;
            f32x2 a[TPL_ND];
            a[0] = dx * w;
            a[1] = dy * w;
            a[2] = dx * dx * hw;
            a[3] = dx * dy * w;
            a[4] = dy * dy * hw;
            f32x2 bwv = (nv - sv) * w;
            int c = 0;
            #pragma unroll
            for (int i = 0; i < TPL_ND; ++i) {
                #pragma unroll
                for (int j = i; j < TPL_ND; ++j) { ata2[c] += a[i] * a[j]; ++c; }
                atb2[i] += a[i] * bwv;
            }
        }

        // ---- issue p+1's LDS gathers NOW; latency hides under the solve ----
        uint2 nb_next[TPL_K];
        if (p + 1 < TPL_PTS) {
            #pragma unroll
            for (int q = 0; q < 4; ++q) {
                nb_next[4*q+0] = lds_pv[ci2[(p + 1) & 1][q].x];
                nb_next[4*q+1] = lds_pv[ci2[(p + 1) & 1][q].y];
                nb_next[4*q+2] = lds_pv[ci2[(p + 1) & 1][q].z];
                nb_next[4*q+3] = lds_pv[ci2[(p + 1) & 1][q].w];
            }
        }

        // horizontal reduce lo+hi
        float ata[15], atb[TPL_ND];
        #pragma unroll
        for (int i = 0; i < 15; ++i) ata[i] = ata2[i].x + ata2[i].y;
        #pragma unroll
        for (int i = 0; i < TPL_ND; ++i) atb[i] = atb2[i].x + atb2[i].y;

        // 5x5 SPD solve, fully unrolled GE; rcp pivots reused in back-sub
        float M[TPL_ND][TPL_ND], r[TPL_ND], pinv[TPL_ND];
        {
            int c = 0;
            #pragma unroll
            for (int i = 0; i < TPL_ND; ++i) {
                #pragma unroll
                for (int j = i; j < TPL_ND; ++j) { M[i][j] = ata[c]; M[j][i] = ata[c]; ++c; }
                r[i] = atb[i];
                M[i][i] += 1e-6f;
            }
        }
        #pragma unroll
        for (int i = 0; i < TPL_ND; ++i) {
            float inv = __builtin_amdgcn_rcpf(M[i][i]);
            pinv[i] = inv;
            #pragma unroll
            for (int j = i + 1; j < TPL_ND; ++j) {
                float f = M[j][i] * inv;
                #pragma unroll
                for (int cc = i + 1; cc < TPL_ND; ++cc) M[j][cc] -= f * M[i][cc];
                r[j] -= f * r[i];
            }
        }
        float sol[TPL_ND];
        #pragma unroll
        for (int i = TPL_ND - 1; i >= 0; --i) {
            float sv2 = r[i];
            #pragma unroll
            for (int cc = i + 1; cc < TPL_ND; ++cc) sv2 -= M[i][cc] * sol[cc];
            sol[i] = sv2 * pinv[i];
        }

        float du = sol[0] * wt0 + sol[1] * wt1 + sol[2] * wt2
                 + sol[3] * wt3 + sol[4] * wt4;
        out[row] = sv + dtv * du;

        // rotate gather pipeline (static indices only)
        if (p + 1 < TPL_PTS) {
            #pragma unroll
            for (int t = 0; t < TPL_K; ++t) nb_cur[t] = nb_next[t];
        }
    }
}

extern "C" void kernel_launch(void* const* d_in, const int* in_sizes, int n_in,
                              void* d_out, int out_size, void* d_ws, size_t ws_size,
                              hipStream_t stream) {
    const float* x          = (const float*)d_in[0];
    const float* points     = (const float*)d_in[1];
    const int*   edge_index = (const int*)d_in[2];
    const float* dtp        = (const float*)d_in[3];
    const float* dist       = (const float*)d_in[4];
    const float* weight     = (const float*)d_in[5];
    float* out = (float*)d_out;

    int total = out_size;                    // B * SIZE = 524288
    int grid  = total / TPL_SPAN;            // 256 blocks (8 per batch)
    size_t lds_bytes = (size_t)TPL_SIZE * sizeof(uint2);  // 128 KB

    tp_lds_kernel<<<grid, TPL_BLK, lds_bytes, stream>>>(
        x, points, edge_index, dtp, dist, weight, out);
}

// Round 20
// 20.268 us; speedup vs baseline: 1.0545x; 1.0545x over previous
//
#include <hip/hip_runtime.h>

#define TPL_SIZE 16384
#define TPL_K 16
#define TPL_ND 5
#define TPL_BLK 512
#define TPL_PTS 4                                  // points per thread
#define TPL_SPAN (TPL_BLK * TPL_PTS)               // 2048 points per block
#define TPL_BPB (TPL_SIZE / TPL_SPAN)              // 8 blocks per batch
#define TPL_NXCD 8

typedef __attribute__((ext_vector_type(2))) float f32x2;

// FINAL = R18 (measured best, 20.28 us; baseline was 66.5). Restored after
// R19's LDS-gather pipelining regressed (+1.1us: rotation copies + register
// pressure outweighed hidden ds_read latency at 8 waves/CU).
// WIN LEDGER:
//  - full-batch u16-packed LDS table {px|py<<16, v} = 128 KB (R7)
//  - XCD-aware block remap: a batch's 8 blocks share one XCD's L2 (R8, -4us)
//  - v_rcp_f32 pivots, reciprocals reused in back-sub (R10, -2.3us)
//  - packed f32x2 2-neighbor accumulation (R11)
//  - depth-2 edge/dist register prefetch pipeline (R18, -0.9us)
//  - 512-thread blocks, (512,2) -> 128-VGPR cap (R7; 1024-thr blocks get
//    64 VGPR regardless of attributes and spill 60-110 MB: R5/R6/R13/R15)
// CLOSED BRANCHES: VALU op-count cuts (R11-null), pair-packed solve (R12),
// global_load_lds DMA (R14), 64KB-table + L2 value gathers at 2 blocks/CU
// (R15/R16), NT streaming hints (R3), LDS-gather pipelining (R19).
// Plateau: ~20.3us vs ~10.5us cold-cache streaming floor; VALU ~22%,
// HBM ~45%, occupancy pinned at 8 waves/CU by the 128 KB table.
__global__ __launch_bounds__(TPL_BLK, 2) void tp_lds_kernel(
    const float* __restrict__ x,
    const float* __restrict__ points,
    const int*   __restrict__ edge_index,
    const float* __restrict__ dtp,
    const float* __restrict__ dist,
    const float* __restrict__ weight,
    float* __restrict__ out)
{
    extern __shared__ uint2 lds_pv[];   // [TPL_SIZE] = 128 KB

    const int tid = threadIdx.x;
    const int blk = blockIdx.x;

    // blk -> (batch, chunk): xcd = blk&7 ; 4 batches per XCD
    const int xcd   = blk & (TPL_NXCD - 1);
    const int batch = xcd * 4 + (blk >> 6);          // [0,32)
    const int chunk = (blk >> 3) & (TPL_BPB - 1);    // [0,8)

    const size_t base = (size_t)batch * TPL_SIZE + chunk * TPL_SPAN;

    // ---- depth-2 prologue: issue points 0 AND 1's streaming loads FIRST
    // (both hide under staging; 16 KB/wave in flight)
    int4   ci2[2][4];
    float4 cw2[2][4];
    #pragma unroll
    for (int d = 0; d < 2; ++d) {
        const size_t rw = base + d * TPL_BLK + tid;
        const int4*   ei = reinterpret_cast<const int4*>(edge_index + rw * TPL_K);
        const float4* dw = reinterpret_cast<const float4*>(dist      + rw * TPL_K);
        #pragma unroll
        for (int q = 0; q < 4; ++q) { ci2[d][q] = ei[q]; cw2[d][q] = dw[q]; }
    }

    // ---- stage + quantize the whole batch table into LDS ----
    // 2 entries/thread/iter, fully coalesced: lane tid -> pb4[k*512+tid]
    {
        const float4* pb4 = reinterpret_cast<const float4*>(points + (size_t)batch * TPL_SIZE * 2);
        const float2* xb2 = reinterpret_cast<const float2*>(x + (size_t)batch * TPL_SIZE);
        uint4* lds4 = reinterpret_cast<uint4*>(lds_pv);
        #pragma unroll
        for (int k = 0; k < TPL_SIZE / (2 * TPL_BLK); ++k) {   // 16 iters
            int g = k * TPL_BLK + tid;        // pair-group index
            float4 pp = pb4[g];               // points for entries 2g, 2g+1
            float2 xv = xb2[g];               // values for entries 2g, 2g+1
            unsigned ux0 = (unsigned)(pp.x * 65536.0f);
            unsigned uy0 = (unsigned)(pp.y * 65536.0f);
            unsigned ux1 = (unsigned)(pp.z * 65536.0f);
            unsigned uy1 = (unsigned)(pp.w * 65536.0f);
            if (ux0 > 65535u) ux0 = 65535u;
            if (uy0 > 65535u) uy0 = 65535u;
            if (ux1 > 65535u) ux1 = 65535u;
            if (uy1 > 65535u) uy1 = 65535u;
            uint4 wv;
            wv.x = ux0 | (uy0 << 16);
            wv.y = __float_as_uint(xv.x);
            wv.z = ux1 | (uy1 << 16);
            wv.w = __float_as_uint(xv.y);
            lds4[g] = wv;
        }
    }
    __syncthreads();

    const float wt0 = weight[0], wt1 = weight[1], wt2 = weight[2],
                wt3 = weight[3], wt4 = weight[4];
    const float dtv = dtp[0];

    #pragma unroll
    for (int p = 0; p < TPL_PTS; ++p) {
        const int    s   = chunk * TPL_SPAN + p * TPL_BLK + tid;
        const size_t row = base + p * TPL_BLK + tid;

        // copy current slot to locals (p&1 is compile-time after unroll)
        int ids[TPL_K];
        float wgt[TPL_K];
        #pragma unroll
        for (int q = 0; q < 4; ++q) {
            ids[4*q+0] = ci2[p & 1][q].x;
            ids[4*q+1] = ci2[p & 1][q].y;
            ids[4*q+2] = ci2[p & 1][q].z;
            ids[4*q+3] = ci2[p & 1][q].w;
            wgt[4*q+0] = cw2[p & 1][q].x;
            wgt[4*q+1] = cw2[p & 1][q].y;
            wgt[4*q+2] = cw2[p & 1][q].z;
            wgt[4*q+3] = cw2[p & 1][q].w;
        }

        // refill the freed slot with point p+2's loads (keeps 2 points of
        // edge/dist in flight through the whole compute)
        if (p + 2 < TPL_PTS) {
            const size_t rw = base + (p + 2) * TPL_BLK + tid;
            const int4*   ei = reinterpret_cast<const int4*>(edge_index + rw * TPL_K);
            const float4* dw = reinterpret_cast<const float4*>(dist      + rw * TPL_K);
            #pragma unroll
            for (int q = 0; q < 4; ++q) { ci2[p & 1][q] = ei[q]; cw2[p & 1][q] = dw[q]; }
        }

        // self point from LDS (same quantization as neighbors)
        uint2 se = lds_pv[s];
        const int sx = (int)(se.x & 0xffffu);
        const int sy = (int)(se.x >> 16);
        const float sv = __uint_as_float(se.y);

        uint2 nb[TPL_K];
        #pragma unroll
        for (int t = 0; t < TPL_K; ++t) nb[t] = lds_pv[ids[t]];

        // ---- packed accumulation: neighbors 2tt (lo) and 2tt+1 (hi) ----
        f32x2 ata2[15], atb2[TPL_ND];
        #pragma unroll
        for (int i = 0; i < 15; ++i) ata2[i] = (f32x2)0.0f;
        #pragma unroll
        for (int i = 0; i < TPL_ND; ++i) atb2[i] = (f32x2)0.0f;

        #pragma unroll
        for (int tt = 0; tt < TPL_K / 2; ++tt) {
            const int t0 = 2 * tt, t1 = 2 * tt + 1;
            int dxi0 = (int)(nb[t0].x & 0xffffu) - sx;
            int dyi0 = (int)(nb[t0].x >> 16)     - sy;
            int dxi1 = (int)(nb[t1].x & 0xffffu) - sx;
            int dyi1 = (int)(nb[t1].x >> 16)     - sy;
            f32x2 dx = (f32x2){(float)dxi0, (float)dxi1} * 0x1p-16f;
            f32x2 dy = (f32x2){(float)dyi0, (float)dyi1} * 0x1p-16f;
            f32x2 w  = {wgt[t0], wgt[t1]};
            f32x2 nv = {__uint_as_float(nb[t0].y), __uint_as_float(nb[t1].y)};
            f32x2 hw = w * 0.5f;
            f32x2 a[TPL_ND];
            a[0] = dx * w;
            a[1] = dy * w;
            a[2] = dx * dx * hw;
            a[3] = dx * dy * w;
            a[4] = dy * dy * hw;
            f32x2 bwv = (nv - sv) * w;
            int c = 0;
            #pragma unroll
            for (int i = 0; i < TPL_ND; ++i) {
                #pragma unroll
                for (int j = i; j < TPL_ND; ++j) { ata2[c] += a[i] * a[j]; ++c; }
                atb2[i] += a[i] * bwv;
            }
        }

        // horizontal reduce lo+hi
        float ata[15], atb[TPL_ND];
        #pragma unroll
        for (int i = 0; i < 15; ++i) ata[i] = ata2[i].x + ata2[i].y;
        #pragma unroll
        for (int i = 0; i < TPL_ND; ++i) atb[i] = atb2[i].x + atb2[i].y;

        // 5x5 SPD solve, fully unrolled GE; rcp pivots reused in back-sub
        float M[TPL_ND][TPL_ND], r[TPL_ND], pinv[TPL_ND];
        {
            int c = 0;
            #pragma unroll
            for (int i = 0; i < TPL_ND; ++i) {
                #pragma unroll
                for (int j = i; j < TPL_ND; ++j) { M[i][j] = ata[c]; M[j][i] = ata[c]; ++c; }
                r[i] = atb[i];
                M[i][i] += 1e-6f;
            }
        }
        #pragma unroll
        for (int i = 0; i < TPL_ND; ++i) {
            float inv = __builtin_amdgcn_rcpf(M[i][i]);
            pinv[i] = inv;
            #pragma unroll
            for (int j = i + 1; j < TPL_ND; ++j) {
                float f = M[j][i] * inv;
                #pragma unroll
                for (int cc = i + 1; cc < TPL_ND; ++cc) M[j][cc] -= f * M[i][cc];
                r[j] -= f * r[i];
            }
        }
        float sol[TPL_ND];
        #pragma unroll
        for (int i = TPL_ND - 1; i >= 0; --i) {
            float sv2 = r[i];
            #pragma unroll
            for (int cc = i + 1; cc < TPL_ND; ++cc) sv2 -= M[i][cc] * sol[cc];
            sol[i] = sv2 * pinv[i];
        }

        float du = sol[0] * wt0 + sol[1] * wt1 + sol[2] * wt2
                 + sol[3] * wt3 + sol[4] * wt4;
        out[row] = sv + dtv * du;
    }
}

extern "C" void kernel_launch(void* const* d_in, const int* in_sizes, int n_in,
                              void* d_out, int out_size, void* d_ws, size_t ws_size,
                              hipStream_t stream) {
    const float* x          = (const float*)d_in[0];
    const float* points     = (const float*)d_in[1];
    const int*   edge_index = (const int*)d_in[2];
    const float* dtp        = (const float*)d_in[3];
    const float* dist       = (const float*)d_in[4];
    const float* weight     = (const float*)d_in[5];
    float* out = (float*)d_out;

    int total = out_size;                    // B * SIZE = 524288
    int grid  = total / TPL_SPAN;            // 256 blocks (8 per batch)
    size_t lds_bytes = (size_t)TPL_SIZE * sizeof(uint2);  // 128 KB

    tp_lds_kernel<<<grid, TPL_BLK, lds_bytes, stream>>>(
        x, points, edge_index, dtp, dist, weight, out);
}